// Round 13
// baseline (78.467 us; speedup 1.0000x reference)
//
#include <hip/hip_runtime.h>
#include <hip/hip_fp8.h>

typedef float    f32x16 __attribute__((ext_vector_type(16)));
typedef _Float16 f16x8  __attribute__((ext_vector_type(8)));
typedef long     i64;

#define NWAVES 4
#define TPW 4
#define TILES_PER_BLOCK (NWAVES * TPW)
#define W1_LDS 32768

// ---- fp8 e4m3 helpers (HW cvt on gfx950) ----
__device__ __forceinline__ uint32_t enc4_fp8(float a, float b, float c, float d) {
#if __has_builtin(__builtin_amdgcn_cvt_pk_fp8_f32)
    int w = __builtin_amdgcn_cvt_pk_fp8_f32(a, b, 0, false);
    w     = __builtin_amdgcn_cvt_pk_fp8_f32(c, d, w, true);
    return (uint32_t)w;
#else
    __hip_fp8_e4m3 e0(a), e1(b), e2(c), e3(d);
    return (uint32_t)e0.__x | ((uint32_t)e1.__x << 8) |
           ((uint32_t)e2.__x << 16) | ((uint32_t)e3.__x << 24);
#endif
}

__device__ __forceinline__ void dec4_fp8f(uint32_t w, float* o) {
#if __has_builtin(__builtin_amdgcn_cvt_pk_f32_fp8)
    const auto f01 = __builtin_amdgcn_cvt_pk_f32_fp8((int)w, false);
    const auto f23 = __builtin_amdgcn_cvt_pk_f32_fp8((int)w, true);
    o[0] = f01[0]; o[1] = f01[1]; o[2] = f23[0]; o[3] = f23[1];
#else
    #pragma unroll
    for (int j = 0; j < 4; ++j) {
        __hip_fp8_e4m3 t; t.__x = (unsigned char)(w >> (8 * j));
        o[j] = (float)t;
    }
#endif
}

__device__ __forceinline__ i64 mk64(uint32_t lo, uint32_t hi) {
    return (i64)(((unsigned long long)hi << 32) | (unsigned long long)lo);
}

// async gather: per-lane global address -> LDS at (dst + lane*16), zero VGPR cost
__device__ __forceinline__ void gl_lds16(const void* g, void* l) {
    __builtin_amdgcn_global_load_lds(
        (const __attribute__((address_space(1))) void*)g,
        (__attribute__((address_space(3))) void*)l, 16, 0, 0);
}

// ---------------- prep A: f32 node tables -> fp8 tables in d_ws ----------------
__global__ __launch_bounds__(256) void prep_fp8(
    const float* __restrict__ zi, const float* __restrict__ zj,
    uint2* __restrict__ zif8, uint2* __restrict__ zjf8, const int nChunkPer)
{
    const int stride = gridDim.x * blockDim.x;
    for (int c = blockIdx.x * blockDim.x + threadIdx.x; c < 2 * nChunkPer; c += stride) {
        const float* s;
        uint2* d;
        int cc;
        if (c < nChunkPer) { cc = c; s = zi + (size_t)cc * 8; d = zif8 + cc; }
        else { cc = c - nChunkPer; s = zj + (size_t)cc * 8; d = zjf8 + cc; }
        const float4 a0 = *reinterpret_cast<const float4*>(s);
        const float4 a1 = *reinterpret_cast<const float4*>(s + 4);
        uint2 w;
        w.x = enc4_fp8(a0.x, a0.y, a0.z, a0.w);
        w.y = enc4_fp8(a1.x, a1.y, a1.z, a1.w);
        *d = w;
    }
}

// ---------------- prep B: W1 -> fp8 hi + fp8 residual*16, k-permuted pack ----
__global__ __launch_bounds__(256) void prep_w1(
    const float* __restrict__ W1, uint4* __restrict__ w1pack)
{
    const int c = blockIdx.x * blockDim.x + threadIdx.x;
    if (c >= 2048) return;
    const int n  = c >> 4, q = c & 15;
    const int kk = q >> 1, lq = q & 1;
    const int kbase = (kk < 4) ? (lq * 32 + kk * 8) : (64 + lq * 32 + (kk - 4) * 8);
    const float* w = W1 + n * 128 + kbase;
    const float4 w0 = *reinterpret_cast<const float4*>(w);
    const float4 w1 = *reinterpret_cast<const float4*>(w + 4);
    const uint32_t h0 = enc4_fp8(w0.x, w0.y, w0.z, w0.w);
    const uint32_t h1 = enc4_fp8(w1.x, w1.y, w1.z, w1.w);
    float d0[4], d1[4];
    dec4_fp8f(h0, d0);
    dec4_fp8f(h1, d1);
    const uint32_t r0 = enc4_fp8((w0.x - d0[0]) * 16.0f, (w0.y - d0[1]) * 16.0f,
                                 (w0.z - d0[2]) * 16.0f, (w0.w - d0[3]) * 16.0f);
    const uint32_t r1 = enc4_fp8((w1.x - d1[0]) * 16.0f, (w1.y - d1[1]) * 16.0f,
                                 (w1.z - d1[2]) * 16.0f, (w1.w - d1[3]) * 16.0f);
    uint4 o; o.x = h0; o.y = h1; o.z = r0; o.w = r1;
    w1pack[c] = o;
}

// ---------------- main ----------------
// Per edge: raw = concat(zi[src] (64), zj[dst] (64));
// hid = relu(raw @ W1^T + b1) [128]; score = sigmoid(hid . W3 + b3).
// neg_score == pos_score (source bug: both scored from raw_pos).
// FP8 path: A-tiles async-staged global->LDS (double-buffered, counted vmcnt),
// fp8 MFMA with W1 = hi + res/16. All tiles/edges clamped (no divergence),
// stores unconditional -> constant vmcnt profile per iteration.
template<bool FP8>
__global__ __launch_bounds__(256) void graphlp_mfma(
    const float* __restrict__ zi, const float* __restrict__ zj,
    const unsigned char* __restrict__ zif8, const unsigned char* __restrict__ zjf8,
    const uint4* __restrict__ w1pack,
    const float* __restrict__ W1, const float* __restrict__ b1p,
    const float* __restrict__ W3, const float* __restrict__ b3p,
    const int* __restrict__ psrc, const int* __restrict__ pdst,
    float* __restrict__ out, const int nEdges, const int nTiles)
{
    // [0,32K): W1 pack (hi/res fp8, swizzled). [32K,64K): 4 waves x 2 x 4KB staging.
    __shared__ char ldsbuf[65536];
    char* lds = ldsbuf;
    const int tid = threadIdx.x;

    if constexpr (FP8) {
        #pragma unroll
        for (int i = 0; i < 8; ++i) {
            const int ch = tid + i * 256;   // 0..2047
            const int n  = ch >> 4;
            const int q  = ch & 15;
            const uint4 v = w1pack[ch];
            const int off = n * 256 + ((q * 16) ^ ((n & 7) << 4));
            *reinterpret_cast<uint4*>(lds + off) = v;
        }
    } else {
        #pragma unroll
        for (int i = 0; i < 8; ++i) {
            const int ch  = tid + i * 256;
            const int row = ch >> 4;
            const int kg  = ch & 15;
            const float* s = W1 + row * 128 + kg * 8;
            const float4 a0 = *reinterpret_cast<const float4*>(s);
            const float4 a1 = *reinterpret_cast<const float4*>(s + 4);
            f16x8 v;
            v[0]=(_Float16)a0.x; v[1]=(_Float16)a0.y; v[2]=(_Float16)a0.z; v[3]=(_Float16)a0.w;
            v[4]=(_Float16)a1.x; v[5]=(_Float16)a1.y; v[6]=(_Float16)a1.z; v[7]=(_Float16)a1.w;
            const int off = row * 256 + ((kg * 16) ^ ((row & 7) << 4));
            *reinterpret_cast<f16x8*>(lds + off) = v;
        }
    }
    __syncthreads();

    const int lane = tid & 63;
    const int wav  = tid >> 6;
    const int lr   = lane & 31;   // edge-row / n-col within 32
    const int lq   = lane >> 5;   // k-half selector

    float b1v[4], w3v[4];
    #pragma unroll
    for (int nb = 0; nb < 4; ++nb) {
        b1v[nb] = b1p[nb * 32 + lr];
        w3v[nb] = W3[nb * 32 + lr];
    }
    const float b3 = b3p[0];

    const int nT1 = nTiles - 1;
    const int gb  = blockIdx.x * TILES_PER_BLOCK + wav;

    if constexpr (FP8) {
        // ---- prologue: preload ALL tile indices (8 VGPR), stage tile0 ----
        int sia[TPW], dia[TPW];
        #pragma unroll
        for (int t = 0; t < TPW; ++t) {
            const int gt = min(gb + t * NWAVES, nT1);
            const int et = min(gt * 32 + lr, nEdges - 1);
            sia[t] = psrc[et];
            dia[t] = pdst[et];
        }
        char* stage = ldsbuf + W1_LDS + wav * 8192;
        {
            const unsigned char* sp = zif8 + (size_t)sia[0] * 64 + lq * 16;
            const unsigned char* dp = zjf8 + (size_t)dia[0] * 64 + lq * 16;
            gl_lds16(sp,      stage);
            gl_lds16(sp + 32, stage + 1024);
            gl_lds16(dp,      stage + 2048);
            gl_lds16(dp + 32, stage + 3072);
        }

        #pragma unroll
        for (int t = 0; t < TPW; ++t) {
            const int g = min(gb + t * NWAVES, nT1);

            // stage tile t+1 into the other buffer (last iter: restage current;
            // harmless, keeps the vmcnt profile constant)
            {
                const int tn = (t + 1 < TPW) ? (t + 1) : t;
                char* dst = stage + ((t + 1) & 1) * 4096;
                const unsigned char* sp = zif8 + (size_t)sia[tn] * 64 + lq * 16;
                const unsigned char* dp = zjf8 + (size_t)dia[tn] * 64 + lq * 16;
                gl_lds16(sp,      dst);
                gl_lds16(sp + 32, dst + 1024);
                gl_lds16(dp,      dst + 2048);
                gl_lds16(dp + 32, dst + 3072);
            }

            // wait for stage(t) only; stage(t+1) [4 loads] (+1 store for t>0)
            // stays in flight across this tile's compute
            if (t == 0) asm volatile("s_waitcnt vmcnt(4)" ::: "memory");
            else        asm volatile("s_waitcnt vmcnt(5)" ::: "memory");
            __builtin_amdgcn_sched_barrier(0);

            // A operands from staged LDS (chunk-major: c*512 + lr*16)
            const char* rb = stage + (t & 1) * 4096 + lq * 1024 + lr * 16;
            const uint4 as0 = *reinterpret_cast<const uint4*>(rb);          // aop0,1
            const uint4 as1 = *reinterpret_cast<const uint4*>(rb + 512);    // aop2,3
            const uint4 ad0 = *reinterpret_cast<const uint4*>(rb + 2048);   // aop4,5
            const uint4 ad1 = *reinterpret_cast<const uint4*>(rb + 2560);   // aop6,7
            i64 aop[8];
            aop[0] = mk64(as0.x, as0.y); aop[1] = mk64(as0.z, as0.w);
            aop[2] = mk64(as1.x, as1.y); aop[3] = mk64(as1.z, as1.w);
            aop[4] = mk64(ad0.x, ad0.y); aop[5] = mk64(ad0.z, ad0.w);
            aop[6] = mk64(ad1.x, ad1.y); aop[7] = mk64(ad1.z, ad1.w);

            float pr[16];
            #pragma unroll
            for (int r = 0; r < 16; ++r) pr[r] = 0.0f;

            #pragma unroll
            for (int nb = 0; nb < 4; ++nb) {
                const float bb = b1v[nb];
                f32x16 acc, accr;
                #pragma unroll
                for (int r = 0; r < 16; ++r) { acc[r] = bb; accr[r] = 0.0f; }
                const int n   = nb * 32 + lr;
                const int nsw = (n & 7) << 4;
                const int nbase = n * 256;
                __builtin_amdgcn_s_setprio(1);
                #pragma unroll
                for (int kk = 0; kk < 8; ++kk) {
                    const int off = nbase + (((kk * 2 + lq) * 16) ^ nsw);
                    const uint4 w = *reinterpret_cast<const uint4*>(lds + off);
                    acc  = __builtin_amdgcn_mfma_f32_32x32x16_fp8_fp8(
                               aop[kk], mk64(w.x, w.y), acc,  0, 0, 0);
                    accr = __builtin_amdgcn_mfma_f32_32x32x16_fp8_fp8(
                               aop[kk], mk64(w.z, w.w), accr, 0, 0, 0);
                }
                __builtin_amdgcn_s_setprio(0);
                const float ww = w3v[nb];
                #pragma unroll
                for (int r = 0; r < 16; ++r) {
                    const float h = fmaf(accr[r], 0.0625f, acc[r]);
                    pr[r] = fmaf(fmaxf(h, 0.0f), ww, pr[r]);
                }
            }

            // fold-reduce over the 32 n-lanes
            float p8[8];
            #pragma unroll
            for (int r = 0; r < 8; ++r) {
                const float lo = pr[r], hi = pr[r + 8];
                const float sent = (lane & 1) ? lo : hi;
                const float got  = __shfl_xor(sent, 1);
                p8[r] = ((lane & 1) ? hi : lo) + got;
            }
            float p4[4];
            #pragma unroll
            for (int r = 0; r < 4; ++r) {
                const float lo = p8[r], hi = p8[r + 4];
                const float sent = (lane & 2) ? lo : hi;
                const float got  = __shfl_xor(sent, 2);
                p4[r] = ((lane & 2) ? hi : lo) + got;
            }
            float p2[2];
            #pragma unroll
            for (int r = 0; r < 2; ++r) {
                const float lo = p4[r], hi = p4[r + 2];
                const float sent = (lane & 4) ? lo : hi;
                const float got  = __shfl_xor(sent, 4);
                p2[r] = ((lane & 4) ? hi : lo) + got;
            }
            float p1;
            {
                const float lo = p2[0], hi = p2[1];
                const float sent = (lane & 8) ? lo : hi;
                const float got  = __shfl_xor(sent, 8);
                p1 = ((lane & 8) ? hi : lo) + got;
            }
            p1 += __shfl_xor(p1, 16);

            const int rid = 8 * (lane & 1) + 4 * ((lane >> 1) & 1)
                          + 2 * ((lane >> 2) & 1) + ((lane >> 3) & 1);
            const int m  = (rid & 3) + 8 * (rid >> 2) + 4 * lq;
            const int eoc = min(g * 32 + m, nEdges - 1);   // clamp: duplicate
            const float sc = 1.0f / (1.0f + __expf(-(p1 + b3)));  // writes identical
            out[(lane & 16) ? (nEdges + eoc) : eoc] = sc;  // unconditional: 1 store
        }
    } else {
        // f32 fallback (r4-proven f16 path, guarded stores)
        int si = 0, di = 0;
        {
            const int g0 = gb;
            if (g0 < nTiles) {
                const int e = min(g0 * 32 + lr, nEdges - 1);
                si = psrc[e]; di = pdst[e];
            }
        }
        for (int t = 0; t < TPW; ++t) {
            const int g = gb + t * NWAVES;
            if (g >= nTiles) break;
            int si_n = 0, di_n = 0;
            if (t + 1 < TPW) {
                const int gn = g + NWAVES;
                if (gn < nTiles) {
                    const int en = min(gn * 32 + lr, nEdges - 1);
                    si_n = psrc[en]; di_n = pdst[en];
                }
            }
            f16x8 afrag[8];
            const float* __restrict__ sp = zi + (size_t)si * 64;
            const float* __restrict__ dp = zj + (size_t)di * 64;
            #pragma unroll
            for (int kk = 0; kk < 8; ++kk) {
                const int kb = kk * 16 + lq * 8;
                const float* p = (kk < 4) ? (sp + kb) : (dp + kb - 64);
                const float4 a0 = *reinterpret_cast<const float4*>(p);
                const float4 a1 = *reinterpret_cast<const float4*>(p + 4);
                f16x8 v;
                v[0]=(_Float16)a0.x; v[1]=(_Float16)a0.y; v[2]=(_Float16)a0.z; v[3]=(_Float16)a0.w;
                v[4]=(_Float16)a1.x; v[5]=(_Float16)a1.y; v[6]=(_Float16)a1.z; v[7]=(_Float16)a1.w;
                afrag[kk] = v;
            }
            float pr[16];
            #pragma unroll
            for (int r = 0; r < 16; ++r) pr[r] = 0.0f;
            #pragma unroll
            for (int nbp = 0; nbp < 2; ++nbp) {
                const float bb0 = b1v[2*nbp], bb1 = b1v[2*nbp + 1];
                f32x16 acc0, acc1;
                #pragma unroll
                for (int r = 0; r < 16; ++r) { acc0[r] = bb0; acc1[r] = bb1; }
                const int n0 = (2*nbp)     * 32 + lr;
                const int n1 = (2*nbp + 1) * 32 + lr;
                #pragma unroll
                for (int kk = 0; kk < 8; ++kk) {
                    const int kx = kk * 32 + lq * 16;
                    const f16x8 bf0 = *reinterpret_cast<const f16x8*>(
                        lds + n0 * 256 + (kx ^ ((n0 & 7) << 4)));
                    const f16x8 bf1 = *reinterpret_cast<const f16x8*>(
                        lds + n1 * 256 + (kx ^ ((n1 & 7) << 4)));
                    acc0 = __builtin_amdgcn_mfma_f32_32x32x16_f16(afrag[kk], bf0, acc0, 0, 0, 0);
                    acc1 = __builtin_amdgcn_mfma_f32_32x32x16_f16(afrag[kk], bf1, acc1, 0, 0, 0);
                }
                const float ww0 = w3v[2*nbp], ww1 = w3v[2*nbp + 1];
                #pragma unroll
                for (int r = 0; r < 16; ++r) {
                    pr[r] = fmaf(fmaxf(acc0[r], 0.0f), ww0, pr[r]);
                    pr[r] = fmaf(fmaxf(acc1[r], 0.0f), ww1, pr[r]);
                }
            }
            float p8[8];
            #pragma unroll
            for (int r = 0; r < 8; ++r) {
                const float lo = pr[r], hi = pr[r + 8];
                const float sent = (lane & 1) ? lo : hi;
                const float got  = __shfl_xor(sent, 1);
                p8[r] = ((lane & 1) ? hi : lo) + got;
            }
            float p4[4];
            #pragma unroll
            for (int r = 0; r < 4; ++r) {
                const float lo = p8[r], hi = p8[r + 4];
                const float sent = (lane & 2) ? lo : hi;
                const float got  = __shfl_xor(sent, 2);
                p4[r] = ((lane & 2) ? hi : lo) + got;
            }
            float p2[2];
            #pragma unroll
            for (int r = 0; r < 2; ++r) {
                const float lo = p4[r], hi = p4[r + 2];
                const float sent = (lane & 4) ? lo : hi;
                const float got  = __shfl_xor(sent, 4);
                p2[r] = ((lane & 4) ? hi : lo) + got;
            }
            float p1;
            {
                const float lo = p2[0], hi = p2[1];
                const float sent = (lane & 8) ? lo : hi;
                const float got  = __shfl_xor(sent, 8);
                p1 = ((lane & 8) ? hi : lo) + got;
            }
            p1 += __shfl_xor(p1, 16);
            const int rid = 8 * (lane & 1) + 4 * ((lane >> 1) & 1)
                          + 2 * ((lane >> 2) & 1) + ((lane >> 3) & 1);
            const int m  = (rid & 3) + 8 * (rid >> 2) + 4 * lq;
            const int eo = g * 32 + m;
            if (eo < nEdges) {
                const float sc = 1.0f / (1.0f + __expf(-(p1 + b3)));
                if (lane & 16) out[nEdges + eo] = sc;
                else           out[eo] = sc;
            }
            si = si_n; di = di_n;
        }
    }
}

extern "C" void kernel_launch(void* const* d_in, const int* in_sizes, int n_in,
                              void* d_out, int out_size, void* d_ws, size_t ws_size,
                              hipStream_t stream)
{
    const float* zi = (const float*)d_in[0];
    const float* zj = (const float*)d_in[1];
    // d_in[2] = zn  (unused: neg path is dead code in the reference)
    const float* W1 = (const float*)d_in[3];
    const float* b1 = (const float*)d_in[4];
    const float* W3 = (const float*)d_in[5];
    const float* b3 = (const float*)d_in[6];
    const int* psrc = (const int*)d_in[7];
    const int* pdst = (const int*)d_in[8];
    float* out = (float*)d_out;

    const int nEdges = in_sizes[7];
    const int nNodesI = in_sizes[0] / 64;   // zi rows
    const int nNodesJ = in_sizes[1] / 64;   // zj rows
    const int nTiles = (nEdges + 31) / 32;
    const int nBlocks = (nTiles + TILES_PER_BLOCK - 1) / TILES_PER_BLOCK;

    const size_t bytesI = (size_t)nNodesI * 64;   // 1 byte per element
    const size_t bytesJ = (size_t)nNodesJ * 64;
    const size_t bytesW = 2048 * 16;              // W1 hi/res pack (32 KiB)
    const bool useF8 = (ws_size >= bytesI + bytesJ + bytesW);

    if (useF8) {
        unsigned char* zif8 = (unsigned char*)d_ws;
        unsigned char* zjf8 = (unsigned char*)d_ws + bytesI;
        uint4* w1pack = (uint4*)((unsigned char*)d_ws + bytesI + bytesJ);
        const int nChunkPer = nNodesI * 64 / 8;
        hipLaunchKernelGGL(prep_fp8, dim3(2048), dim3(256), 0, stream,
                           zi, zj, (uint2*)zif8, (uint2*)zjf8, nChunkPer);
        hipLaunchKernelGGL(prep_w1, dim3(8), dim3(256), 0, stream, W1, w1pack);
        hipLaunchKernelGGL((graphlp_mfma<true>), dim3(nBlocks), dim3(256), 0, stream,
                           zi, zj, zif8, zjf8, w1pack, W1, b1, W3, b3, psrc, pdst,
                           out, nEdges, nTiles);
    } else {
        hipLaunchKernelGGL((graphlp_mfma<false>), dim3(nBlocks), dim3(256), 0, stream,
                           zi, zj, (const unsigned char*)nullptr, (const unsigned char*)nullptr,
                           (const uint4*)nullptr, W1, b1, W3, b3, psrc, pdst,
                           out, nEdges, nTiles);
    }
}

// Round 15
// 75.375 us; speedup vs baseline: 1.0410x; 1.0410x over previous
//
#include <hip/hip_runtime.h>
#include <hip/hip_fp8.h>

typedef float    f32x16 __attribute__((ext_vector_type(16)));
typedef _Float16 f16x8  __attribute__((ext_vector_type(8)));
typedef long     i64;

#define NWAVES 4
#define TPW 4
#define TILES_PER_BLOCK (NWAVES * TPW)

// ---- fp8 e4m3 helpers (HW cvt on gfx950) ----
__device__ __forceinline__ uint32_t enc4_fp8(float a, float b, float c, float d) {
#if __has_builtin(__builtin_amdgcn_cvt_pk_fp8_f32)
    int w = __builtin_amdgcn_cvt_pk_fp8_f32(a, b, 0, false);
    w     = __builtin_amdgcn_cvt_pk_fp8_f32(c, d, w, true);
    return (uint32_t)w;
#else
    __hip_fp8_e4m3 e0(a), e1(b), e2(c), e3(d);
    return (uint32_t)e0.__x | ((uint32_t)e1.__x << 8) |
           ((uint32_t)e2.__x << 16) | ((uint32_t)e3.__x << 24);
#endif
}

__device__ __forceinline__ void dec4_fp8f(uint32_t w, float* o) {
#if __has_builtin(__builtin_amdgcn_cvt_pk_f32_fp8)
    const auto f01 = __builtin_amdgcn_cvt_pk_f32_fp8((int)w, false);
    const auto f23 = __builtin_amdgcn_cvt_pk_f32_fp8((int)w, true);
    o[0] = f01[0]; o[1] = f01[1]; o[2] = f23[0]; o[3] = f23[1];
#else
    #pragma unroll
    for (int j = 0; j < 4; ++j) {
        __hip_fp8_e4m3 t; t.__x = (unsigned char)(w >> (8 * j));
        o[j] = (float)t;
    }
#endif
}

__device__ __forceinline__ i64 mk64(uint32_t lo, uint32_t hi) {
    return (i64)(((unsigned long long)hi << 32) | (unsigned long long)lo);
}

// ---------------- prep A: f32 node tables -> fp8 tables in d_ws ----------------
__global__ __launch_bounds__(256) void prep_fp8(
    const float* __restrict__ zi, const float* __restrict__ zj,
    uint2* __restrict__ zif8, uint2* __restrict__ zjf8, const int nChunkPer)
{
    const int stride = gridDim.x * blockDim.x;
    for (int c = blockIdx.x * blockDim.x + threadIdx.x; c < 2 * nChunkPer; c += stride) {
        const float* s;
        uint2* d;
        int cc;
        if (c < nChunkPer) { cc = c; s = zi + (size_t)cc * 8; d = zif8 + cc; }
        else { cc = c - nChunkPer; s = zj + (size_t)cc * 8; d = zjf8 + cc; }
        const float4 a0 = *reinterpret_cast<const float4*>(s);
        const float4 a1 = *reinterpret_cast<const float4*>(s + 4);
        uint2 w;
        w.x = enc4_fp8(a0.x, a0.y, a0.z, a0.w);
        w.y = enc4_fp8(a1.x, a1.y, a1.z, a1.w);
        *d = w;
    }
}

// ---------------- prep B: W1 -> fp8 hi + fp8 residual*16, k-permuted pack ----
__global__ __launch_bounds__(256) void prep_w1(
    const float* __restrict__ W1, uint4* __restrict__ w1pack)
{
    const int c = blockIdx.x * blockDim.x + threadIdx.x;
    if (c >= 2048) return;
    const int n  = c >> 4, q = c & 15;
    const int kk = q >> 1, lq = q & 1;
    const int kbase = (kk < 4) ? (lq * 32 + kk * 8) : (64 + lq * 32 + (kk - 4) * 8);
    const float* w = W1 + n * 128 + kbase;
    const float4 w0 = *reinterpret_cast<const float4*>(w);
    const float4 w1 = *reinterpret_cast<const float4*>(w + 4);
    const uint32_t h0 = enc4_fp8(w0.x, w0.y, w0.z, w0.w);
    const uint32_t h1 = enc4_fp8(w1.x, w1.y, w1.z, w1.w);
    float d0[4], d1[4];
    dec4_fp8f(h0, d0);
    dec4_fp8f(h1, d1);
    const uint32_t r0 = enc4_fp8((w0.x - d0[0]) * 16.0f, (w0.y - d0[1]) * 16.0f,
                                 (w0.z - d0[2]) * 16.0f, (w0.w - d0[3]) * 16.0f);
    const uint32_t r1 = enc4_fp8((w1.x - d1[0]) * 16.0f, (w1.y - d1[1]) * 16.0f,
                                 (w1.z - d1[2]) * 16.0f, (w1.w - d1[3]) * 16.0f);
    uint4 o; o.x = h0; o.y = h1; o.z = r0; o.w = r1;
    w1pack[c] = o;
}

// ---------------- main ----------------
// Per edge: raw = concat(zi[src] (64), zj[dst] (64));
// hid = relu(raw @ W1^T + b1) [128]; score = sigmoid(hid . W3 + b3).
// neg_score == pos_score (source bug: both scored from raw_pos).
// r11 compute core (proven 72us / absmax 0.0117) + depth-1 register prefetch
// of next tile's raw fp8 A (16 VGPR) so gathers hide under MFMA+epilogue.
// No launch_bounds min-wave forcing (r8's spill lesson). LDS stays 32 KiB.
template<bool FP8>
__global__ __launch_bounds__(256) void graphlp_mfma(
    const float* __restrict__ zi, const float* __restrict__ zj,
    const unsigned char* __restrict__ zif8, const unsigned char* __restrict__ zjf8,
    const uint4* __restrict__ w1pack,
    const float* __restrict__ W1, const float* __restrict__ b1p,
    const float* __restrict__ W3, const float* __restrict__ b3p,
    const int* __restrict__ psrc, const int* __restrict__ pdst,
    float* __restrict__ out, const int nEdges, const int nTiles)
{
    // 32 KiB LDS; FP8: packed hi/res chunks at n*256 + ((q*16) ^ ((n&7)<<4))
    __shared__ uint4 w1s[2048];
    char* lds = reinterpret_cast<char*>(w1s);
    const int tid = threadIdx.x;

    if constexpr (FP8) {
        #pragma unroll
        for (int i = 0; i < 8; ++i) {
            const int ch = tid + i * 256;   // 0..2047
            const int n  = ch >> 4;
            const int q  = ch & 15;
            const uint4 v = w1pack[ch];
            const int off = n * 256 + ((q * 16) ^ ((n & 7) << 4));
            *reinterpret_cast<uint4*>(lds + off) = v;
        }
    } else {
        #pragma unroll
        for (int i = 0; i < 8; ++i) {
            const int ch  = tid + i * 256;
            const int row = ch >> 4;
            const int kg  = ch & 15;
            const float* s = W1 + row * 128 + kg * 8;
            const float4 a0 = *reinterpret_cast<const float4*>(s);
            const float4 a1 = *reinterpret_cast<const float4*>(s + 4);
            f16x8 v;
            v[0]=(_Float16)a0.x; v[1]=(_Float16)a0.y; v[2]=(_Float16)a0.z; v[3]=(_Float16)a0.w;
            v[4]=(_Float16)a1.x; v[5]=(_Float16)a1.y; v[6]=(_Float16)a1.z; v[7]=(_Float16)a1.w;
            const int off = row * 256 + ((kg * 16) ^ ((row & 7) << 4));
            *reinterpret_cast<f16x8*>(lds + off) = v;
        }
    }
    __syncthreads();

    const int lane = tid & 63;
    const int wav  = tid >> 6;
    const int lr   = lane & 31;   // edge-row / n-col within 32
    const int lq   = lane >> 5;   // k-half selector

    float b1v[4], w3v[4];
    #pragma unroll
    for (int nb = 0; nb < 4; ++nb) {
        b1v[nb] = b1p[nb * 32 + lr];
        w3v[nb] = W3[nb * 32 + lr];
    }
    const float b3 = b3p[0];

    const int nT1 = nTiles - 1;
    const int gb  = blockIdx.x * TILES_PER_BLOCK + wav;

    if constexpr (FP8) {
        // ---- prologue: idx(t0), idx(t1); raw fp8 A(t0) in px ----
        uint2 px[8];
        int si1, di1;
        {
            const int g0 = min(gb, nT1);
            const int e0 = min(g0 * 32 + lr, nEdges - 1);
            const int si0 = psrc[e0], di0 = pdst[e0];
            const int g1 = min(gb + NWAVES, nT1);
            const int e1 = min(g1 * 32 + lr, nEdges - 1);
            si1 = psrc[e1]; di1 = pdst[e1];
            const unsigned char* sp = zif8 + (size_t)si0 * 64 + lq * 32;
            const unsigned char* dp = zjf8 + (size_t)di0 * 64 + lq * 32;
            const uint4 s0 = *reinterpret_cast<const uint4*>(sp);
            const uint4 s1 = *reinterpret_cast<const uint4*>(sp + 16);
            const uint4 d0 = *reinterpret_cast<const uint4*>(dp);
            const uint4 d1 = *reinterpret_cast<const uint4*>(dp + 16);
            px[0].x=s0.x; px[0].y=s0.y; px[1].x=s0.z; px[1].y=s0.w;
            px[2].x=s1.x; px[2].y=s1.y; px[3].x=s1.z; px[3].y=s1.w;
            px[4].x=d0.x; px[4].y=d0.y; px[5].x=d0.z; px[5].y=d0.w;
            px[6].x=d1.x; px[6].y=d1.y; px[7].x=d1.z; px[7].y=d1.w;
        }

        #pragma unroll
        for (int t = 0; t < TPW; ++t) {
            const int g = min(gb + t * NWAVES, nT1);

            // issue next tile's raw A gathers NOW (hide under MFMA+epilogue)
            uint2 pn[8];
            {
                const unsigned char* sp = zif8 + (size_t)si1 * 64 + lq * 32;
                const unsigned char* dp = zjf8 + (size_t)di1 * 64 + lq * 32;
                const uint4 s0 = *reinterpret_cast<const uint4*>(sp);
                const uint4 s1 = *reinterpret_cast<const uint4*>(sp + 16);
                const uint4 d0 = *reinterpret_cast<const uint4*>(dp);
                const uint4 d1 = *reinterpret_cast<const uint4*>(dp + 16);
                pn[0].x=s0.x; pn[0].y=s0.y; pn[1].x=s0.z; pn[1].y=s0.w;
                pn[2].x=s1.x; pn[2].y=s1.y; pn[3].x=s1.z; pn[3].y=s1.w;
                pn[4].x=d0.x; pn[4].y=d0.y; pn[5].x=d0.z; pn[5].y=d0.w;
                pn[6].x=d1.x; pn[6].y=d1.y; pn[7].x=d1.z; pn[7].y=d1.w;
            }
            // prefetch idx for t+2 (clamped)
            int si2, di2;
            {
                const int g2 = min(gb + (t + 2) * NWAVES, nT1);
                const int e2 = min(g2 * 32 + lr, nEdges - 1);
                si2 = psrc[e2]; di2 = pdst[e2];
            }

            float pr[16];
            #pragma unroll
            for (int r = 0; r < 16; ++r) pr[r] = 0.0f;

            #pragma unroll
            for (int nb = 0; nb < 4; ++nb) {
                const float bb = b1v[nb];
                f32x16 acc, accr;
                #pragma unroll
                for (int r = 0; r < 16; ++r) { acc[r] = bb; accr[r] = 0.0f; }
                const int n   = nb * 32 + lr;
                const int nsw = (n & 7) << 4;
                const int nbase = n * 256;
                __builtin_amdgcn_s_setprio(1);
                #pragma unroll
                for (int kk = 0; kk < 8; ++kk) {
                    const int off = nbase + (((kk * 2 + lq) * 16) ^ nsw);
                    const uint4 w = *reinterpret_cast<const uint4*>(lds + off);
                    const i64 a = mk64(px[kk].x, px[kk].y);
                    acc  = __builtin_amdgcn_mfma_f32_32x32x16_fp8_fp8(
                               a, mk64(w.x, w.y), acc,  0, 0, 0);
                    accr = __builtin_amdgcn_mfma_f32_32x32x16_fp8_fp8(
                               a, mk64(w.z, w.w), accr, 0, 0, 0);
                }
                __builtin_amdgcn_s_setprio(0);
                const float ww = w3v[nb];
                #pragma unroll
                for (int r = 0; r < 16; ++r) {
                    const float h = fmaf(accr[r], 0.0625f, acc[r]);
                    pr[r] = fmaf(fmaxf(h, 0.0f), ww, pr[r]);
                }
            }

            // fold-reduce over the 32 n-lanes
            float p8[8];
            #pragma unroll
            for (int r = 0; r < 8; ++r) {
                const float lo = pr[r], hi = pr[r + 8];
                const float sent = (lane & 1) ? lo : hi;
                const float got  = __shfl_xor(sent, 1);
                p8[r] = ((lane & 1) ? hi : lo) + got;
            }
            float p4[4];
            #pragma unroll
            for (int r = 0; r < 4; ++r) {
                const float lo = p8[r], hi = p8[r + 4];
                const float sent = (lane & 2) ? lo : hi;
                const float got  = __shfl_xor(sent, 2);
                p4[r] = ((lane & 2) ? hi : lo) + got;
            }
            float p2[2];
            #pragma unroll
            for (int r = 0; r < 2; ++r) {
                const float lo = p4[r], hi = p4[r + 2];
                const float sent = (lane & 4) ? lo : hi;
                const float got  = __shfl_xor(sent, 4);
                p2[r] = ((lane & 4) ? hi : lo) + got;
            }
            float p1;
            {
                const float lo = p2[0], hi = p2[1];
                const float sent = (lane & 8) ? lo : hi;
                const float got  = __shfl_xor(sent, 8);
                p1 = ((lane & 8) ? hi : lo) + got;
            }
            p1 += __shfl_xor(p1, 16);

            const int rid = 8 * (lane & 1) + 4 * ((lane >> 1) & 1)
                          + 2 * ((lane >> 2) & 1) + ((lane >> 3) & 1);
            const int m  = (rid & 3) + 8 * (rid >> 2) + 4 * lq;
            const int eo = min(g * 32 + m, nEdges - 1);
            const float sc = 1.0f / (1.0f + __expf(-(p1 + b3)));
            out[(lane & 16) ? (nEdges + eo) : eo] = sc;

            // rotate pipeline state
            #pragma unroll
            for (int kk = 0; kk < 8; ++kk) px[kk] = pn[kk];
            si1 = si2; di1 = di2;
        }
    } else {
        // f32 fallback (r4-proven f16 path, guarded stores)
        int si = 0, di = 0;
        {
            if (gb < nTiles) {
                const int e = min(gb * 32 + lr, nEdges - 1);
                si = psrc[e]; di = pdst[e];
            }
        }
        for (int t = 0; t < TPW; ++t) {
            const int g = gb + t * NWAVES;
            if (g >= nTiles) break;
            int si_n = 0, di_n = 0;
            if (t + 1 < TPW) {
                const int gn = g + NWAVES;
                if (gn < nTiles) {
                    const int en = min(gn * 32 + lr, nEdges - 1);
                    si_n = psrc[en]; di_n = pdst[en];
                }
            }
            f16x8 afrag[8];
            const float* __restrict__ sp = zi + (size_t)si * 64;
            const float* __restrict__ dp = zj + (size_t)di * 64;
            #pragma unroll
            for (int kk = 0; kk < 8; ++kk) {
                const int kb = kk * 16 + lq * 8;
                const float* p = (kk < 4) ? (sp + kb) : (dp + kb - 64);
                const float4 a0 = *reinterpret_cast<const float4*>(p);
                const float4 a1 = *reinterpret_cast<const float4*>(p + 4);
                f16x8 v;
                v[0]=(_Float16)a0.x; v[1]=(_Float16)a0.y; v[2]=(_Float16)a0.z; v[3]=(_Float16)a0.w;
                v[4]=(_Float16)a1.x; v[5]=(_Float16)a1.y; v[6]=(_Float16)a1.z; v[7]=(_Float16)a1.w;
                afrag[kk] = v;
            }
            float pr[16];
            #pragma unroll
            for (int r = 0; r < 16; ++r) pr[r] = 0.0f;
            #pragma unroll
            for (int nbp = 0; nbp < 2; ++nbp) {
                const float bb0 = b1v[2*nbp], bb1 = b1v[2*nbp + 1];
                f32x16 acc0, acc1;
                #pragma unroll
                for (int r = 0; r < 16; ++r) { acc0[r] = bb0; acc1[r] = bb1; }
                const int n0 = (2*nbp)     * 32 + lr;
                const int n1 = (2*nbp + 1) * 32 + lr;
                #pragma unroll
                for (int kk = 0; kk < 8; ++kk) {
                    const int kx = kk * 32 + lq * 16;
                    const f16x8 bf0 = *reinterpret_cast<const f16x8*>(
                        lds + n0 * 256 + (kx ^ ((n0 & 7) << 4)));
                    const f16x8 bf1 = *reinterpret_cast<const f16x8*>(
                        lds + n1 * 256 + (kx ^ ((n1 & 7) << 4)));
                    acc0 = __builtin_amdgcn_mfma_f32_32x32x16_f16(afrag[kk], bf0, acc0, 0, 0, 0);
                    acc1 = __builtin_amdgcn_mfma_f32_32x32x16_f16(afrag[kk], bf1, acc1, 0, 0, 0);
                }
                const float ww0 = w3v[2*nbp], ww1 = w3v[2*nbp + 1];
                #pragma unroll
                for (int r = 0; r < 16; ++r) {
                    pr[r] = fmaf(fmaxf(acc0[r], 0.0f), ww0, pr[r]);
                    pr[r] = fmaf(fmaxf(acc1[r], 0.0f), ww1, pr[r]);
                }
            }
            float p8[8];
            #pragma unroll
            for (int r = 0; r < 8; ++r) {
                const float lo = pr[r], hi = pr[r + 8];
                const float sent = (lane & 1) ? lo : hi;
                const float got  = __shfl_xor(sent, 1);
                p8[r] = ((lane & 1) ? hi : lo) + got;
            }
            float p4[4];
            #pragma unroll
            for (int r = 0; r < 4; ++r) {
                const float lo = p8[r], hi = p8[r + 4];
                const float sent = (lane & 2) ? lo : hi;
                const float got  = __shfl_xor(sent, 2);
                p4[r] = ((lane & 2) ? hi : lo) + got;
            }
            float p2[2];
            #pragma unroll
            for (int r = 0; r < 2; ++r) {
                const float lo = p4[r], hi = p4[r + 2];
                const float sent = (lane & 4) ? lo : hi;
                const float got  = __shfl_xor(sent, 4);
                p2[r] = ((lane & 4) ? hi : lo) + got;
            }
            float p1;
            {
                const float lo = p2[0], hi = p2[1];
                const float sent = (lane & 8) ? lo : hi;
                const float got  = __shfl_xor(sent, 8);
                p1 = ((lane & 8) ? hi : lo) + got;
            }
            p1 += __shfl_xor(p1, 16);
            const int rid = 8 * (lane & 1) + 4 * ((lane >> 1) & 1)
                          + 2 * ((lane >> 2) & 1) + ((lane >> 3) & 1);
            const int m  = (rid & 3) + 8 * (rid >> 2) + 4 * lq;
            const int eo = g * 32 + m;
            if (eo < nEdges) {
                const float sc = 1.0f / (1.0f + __expf(-(p1 + b3)));
                if (lane & 16) out[nEdges + eo] = sc;
                else           out[eo] = sc;
            }
            si = si_n; di = di_n;
        }
    }
}

extern "C" void kernel_launch(void* const* d_in, const int* in_sizes, int n_in,
                              void* d_out, int out_size, void* d_ws, size_t ws_size,
                              hipStream_t stream)
{
    const float* zi = (const float*)d_in[0];
    const float* zj = (const float*)d_in[1];
    // d_in[2] = zn  (unused: neg path is dead code in the reference)
    const float* W1 = (const float*)d_in[3];
    const float* b1 = (const float*)d_in[4];
    const float* W3 = (const float*)d_in[5];
    const float* b3 = (const float*)d_in[6];
    const int* psrc = (const int*)d_in[7];
    const int* pdst = (const int*)d_in[8];
    float* out = (float*)d_out;

    const int nEdges = in_sizes[7];
    const int nNodesI = in_sizes[0] / 64;   // zi rows
    const int nNodesJ = in_sizes[1] / 64;   // zj rows
    const int nTiles = (nEdges + 31) / 32;
    const int nBlocks = (nTiles + TILES_PER_BLOCK - 1) / TILES_PER_BLOCK;

    const size_t bytesI = (size_t)nNodesI * 64;   // 1 byte per element
    const size_t bytesJ = (size_t)nNodesJ * 64;
    const size_t bytesW = 2048 * 16;              // W1 hi/res pack (32 KiB)
    const bool useF8 = (ws_size >= bytesI + bytesJ + bytesW);

    if (useF8) {
        unsigned char* zif8 = (unsigned char*)d_ws;
        unsigned char* zjf8 = (unsigned char*)d_ws + bytesI;
        uint4* w1pack = (uint4*)((unsigned char*)d_ws + bytesI + bytesJ);
        const int nChunkPer = nNodesI * 64 / 8;
        hipLaunchKernelGGL(prep_fp8, dim3(2048), dim3(256), 0, stream,
                           zi, zj, (uint2*)zif8, (uint2*)zjf8, nChunkPer);
        hipLaunchKernelGGL(prep_w1, dim3(8), dim3(256), 0, stream, W1, w1pack);
        hipLaunchKernelGGL((graphlp_mfma<true>), dim3(nBlocks), dim3(256), 0, stream,
                           zi, zj, zif8, zjf8, w1pack, W1, b1, W3, b3, psrc, pdst,
                           out, nEdges, nTiles);
    } else {
        hipLaunchKernelGGL((graphlp_mfma<false>), dim3(nBlocks), dim3(256), 0, stream,
                           zi, zj, (const unsigned char*)nullptr, (const unsigned char*)nullptr,
                           (const uint4*)nullptr, W1, b1, W3, b3, psrc, pdst,
                           out, nEdges, nTiles);
    }
}